// Round 4
// baseline (218.592 us; speedup 1.0000x reference)
//
#include <hip/hip_runtime.h>
#include <hip/hip_bf16.h>

#define D_MODEL 768
#define NH 12
#define DHd 64
#define NB 2
#define SL 4096
#define BLr (NB*SL)      // 8192 rows
#define N3 (3*D_MODEL)   // 2304
#define QSCALE 0.18033688011112042f   // 0.125 * log2(e): softmax in log2 domain

typedef __bf16 bf16x8 __attribute__((ext_vector_type(8)));
typedef float f32x4 __attribute__((ext_vector_type(4)));
typedef float f32x16 __attribute__((ext_vector_type(16)));
typedef unsigned int u32x4 __attribute__((ext_vector_type(4)));

__device__ __forceinline__ unsigned short f2bf(float f) {
  unsigned int u = __float_as_uint(f);
  u = (u + 0x7FFFu + ((u >> 16) & 1u)) >> 16;
  return (unsigned short)u;
}
__device__ __forceinline__ unsigned short bfc(float f) {
  __bf16 h = (__bf16)f;
  return __builtin_bit_cast(unsigned short, h);
}
__device__ __forceinline__ float fexp2(float x) {
  float r; asm("v_exp_f32 %0, %1" : "=v"(r) : "v"(x)); return r;
}
__device__ __forceinline__ unsigned int pk2(float lo, float hi2) {
  return ((unsigned int)bfc(hi2) << 16) | (unsigned int)bfc(lo);
}
__device__ __forceinline__ float vmax16(const f32x16& v) {
  float a = fmaxf(fmaxf(fmaxf(v[0],v[1]),fmaxf(v[2],v[3])),
                  fmaxf(fmaxf(v[4],v[5]),fmaxf(v[6],v[7])));
  float b = fmaxf(fmaxf(fmaxf(v[8],v[9]),fmaxf(v[10],v[11])),
                  fmaxf(fmaxf(v[12],v[13]),fmaxf(v[14],v[15])));
  return fmaxf(a,b);
}
__device__ __forceinline__ float vsum16(const f32x16& v) {
  float a = (v[0]+v[1])+(v[2]+v[3]);
  float b = (v[4]+v[5])+(v[6]+v[7]);
  float c = (v[8]+v[9])+(v[10]+v[11]);
  float d = (v[12]+v[13])+(v[14]+v[15]);
  return (a+b)+(c+d);
}

// ---------------- prep kernels ----------------
__global__ __launch_bounds__(256) void cast_f32_bf16(const float* __restrict__ in,
                                                     unsigned short* __restrict__ out, int n4) {
  int i = blockIdx.x * 256 + threadIdx.x;
  if (i >= n4) return;
  float4 v = reinterpret_cast<const float4*>(in)[i];
  ushort4 o;
  o.x = f2bf(v.x); o.y = f2bf(v.y); o.z = f2bf(v.z); o.w = f2bf(v.w);
  reinterpret_cast<ushort4*>(out)[i] = o;
}

__global__ __launch_bounds__(256) void transpose_cast(const float* __restrict__ in,
                                                      unsigned short* __restrict__ out,
                                                      int R, int C) {
  __shared__ float t[32][33];
  int c0 = blockIdx.x * 32, r0 = blockIdx.y * 32;
  int tx = threadIdx.x & 31, ty = threadIdx.x >> 5;
  #pragma unroll
  for (int i = 0; i < 32; i += 8) t[ty + i][tx] = in[(size_t)(r0 + ty + i) * C + c0 + tx];
  __syncthreads();
  #pragma unroll
  for (int i = 0; i < 32; i += 8) out[(size_t)(c0 + ty + i) * R + r0 + tx] = f2bf(t[tx][ty + i]);
}

// ---------------- bf16 GEMM: C = A(MxK) * Bt(NxK)^T + bias ----------------
// MODE 0: QKV epilogue -> fragment-tiled Q/K/V stores (tile = [64 lanes][8 bf16])
//   Q/K: idx = ((hb*128 + (l>>5))*4 + (d>>4))*512 + ((l&31) + 32*((d>>3)&1))*8 + (d&7)
//   V:   idx = ((hb*64 + (l>>6))*8 + ((l>>4)&3)*2 + (d>>5))*512 + ((d&31) + 32*((l>>3)&1))*8 + (l&7)
// MODE 1: fp32 epilogue -> Out[row*N+col]
template<int MODE>
__global__ __launch_bounds__(256) void gemm_bf16(const unsigned short* __restrict__ A,
                                                 const unsigned short* __restrict__ Bt,
                                                 const float* __restrict__ bias,
                                                 void* __restrict__ o0, void* __restrict__ o1,
                                                 void* __restrict__ o2,
                                                 int M, int N, int Kdim) {
  constexpr int LDT = 40;
  __shared__ unsigned short As[128 * LDT];
  __shared__ unsigned short Bs[128 * LDT];
  const int tid = threadIdx.x;
  const int lane = tid & 63, wave = tid >> 6;
  const int tm = blockIdx.x * 128, tn = blockIdx.y * 128;
  const int wm = (wave >> 1) * 64, wn = (wave & 1) * 64;
  const int fr = lane & 15, fk8 = (lane >> 4) * 8;
  const int srow = tid >> 2, scol = (tid & 3) * 8;

  f32x4 acc[4][4] = {};

  const unsigned short* Arow0 = A + (size_t)(tm + srow) * Kdim + scol;
  const unsigned short* Arow1 = A + (size_t)(tm + 64 + srow) * Kdim + scol;
  const unsigned short* Brow0 = Bt + (size_t)(tn + srow) * Kdim + scol;
  const unsigned short* Brow1 = Bt + (size_t)(tn + 64 + srow) * Kdim + scol;

  for (int k0 = 0; k0 < Kdim; k0 += 32) {
    ulonglong2 a0 = *(const ulonglong2*)(Arow0 + k0);
    ulonglong2 a1 = *(const ulonglong2*)(Arow1 + k0);
    ulonglong2 b0 = *(const ulonglong2*)(Brow0 + k0);
    ulonglong2 b1 = *(const ulonglong2*)(Brow1 + k0);
    __syncthreads();
    *(ulonglong2*)(As + srow * LDT + scol) = a0;
    *(ulonglong2*)(As + (64 + srow) * LDT + scol) = a1;
    *(ulonglong2*)(Bs + srow * LDT + scol) = b0;
    *(ulonglong2*)(Bs + (64 + srow) * LDT + scol) = b1;
    __syncthreads();

    bf16x8 af[4], bfr[4];
    #pragma unroll
    for (int i = 0; i < 4; i++) {
      af[i]  = *(const bf16x8*)(As + (wm + i * 16 + fr) * LDT + fk8);
      bfr[i] = *(const bf16x8*)(Bs + (wn + i * 16 + fr) * LDT + fk8);
    }
    #pragma unroll
    for (int i = 0; i < 4; i++)
      #pragma unroll
      for (int j = 0; j < 4; j++)
        acc[i][j] = __builtin_amdgcn_mfma_f32_16x16x32_bf16(af[i], bfr[j], acc[i][j], 0, 0, 0);
  }

  const int fq = (lane >> 4) * 4;
  if constexpr (MODE == 0) {
    unsigned short* Qf = (unsigned short*)o0;
    unsigned short* Kf = (unsigned short*)o1;
    unsigned short* Vf = (unsigned short*)o2;
    #pragma unroll
    for (int j = 0; j < 4; j++) {
      int col = tn + wn + j * 16 + fr;
      float bv = bias[col];
      int which = col / D_MODEL;
      int hd = col % D_MODEL;
      int h = hd >> 6, d = hd & 63;
      #pragma unroll
      for (int i = 0; i < 4; i++) {
        #pragma unroll
        for (int r = 0; r < 4; r++) {
          int row = tm + wm + i * 16 + fq + r;
          int b = row >> 12, l = row & 4095;
          float v = acc[i][j][r] + bv;
          size_t hb = (size_t)b * NH + h;
          if (which == 2) {
            size_t off = ((hb * 64 + (l >> 6)) * 8 + ((l >> 4) & 3) * 2 + (d >> 5)) * 512
                       + (size_t)((d & 31) + 32 * ((l >> 3) & 1)) * 8 + (l & 7);
            Vf[off] = bfc(v);
          } else {
            size_t off = ((hb * 128 + (l >> 5)) * 4 + (d >> 4)) * 512
                       + (size_t)((l & 31) + 32 * ((d >> 3) & 1)) * 8 + (d & 7);
            if (which == 0) Qf[off] = bfc(v * QSCALE);
            else            Kf[off] = bfc(v);
          }
        }
      }
    }
  } else {
    float* Out = (float*)o0;
    #pragma unroll
    for (int i = 0; i < 4; i++)
      #pragma unroll
      for (int j = 0; j < 4; j++) {
        int col = tn + wn + j * 16 + fr;
        float bv = bias[col];
        #pragma unroll
        for (int r = 0; r < 4; r++) {
          int row = tm + wm + i * 16 + fq + r;
          Out[(size_t)row * N + col] = acc[i][j][r] + bv;
        }
      }
  }
}

// ---------------- flash attention: no-LDS, fragment-tiled operands ----------
// grid 768 x 256thr (4 independent waves, NO barriers). Block = pair {qi,63-qi}
// of one bh: wave w -> tile tq = (w>>1 ? 63-qi : qi), sub-half w&1 (32 q-rows).
// All operand loads are coalesced 1KB tile loads: addr = tile_base + lane*16.
struct KFrags { bf16x8 a[2][4]; };   // [grp][f] — constant-index only

#define PVSTEP(P, B, VB0, VB1) do {                                        \
    unsigned int u0 = pk2(P[(B)+0], P[(B)+1]);                             \
    unsigned int u1 = pk2(P[(B)+2], P[(B)+3]);                             \
    unsigned int u2 = pk2(P[(B)+4], P[(B)+5]);                             \
    unsigned int u3 = pk2(P[(B)+6], P[(B)+7]);                             \
    unsigned int e0 = __shfl_xor(hi ? u0 : u2, 32);                        \
    unsigned int e1 = __shfl_xor(hi ? u1 : u3, 32);                        \
    u32x4 w;                                                               \
    w[0] = hi ? e0 : u0; w[1] = hi ? e1 : u1;                              \
    w[2] = hi ? u2 : e0; w[3] = hi ? u3 : e1;                              \
    bf16x8 pa = __builtin_bit_cast(bf16x8, w);                             \
    oacc0 = __builtin_amdgcn_mfma_f32_32x32x16_bf16(pa, VB0, oacc0, 0,0,0);\
    oacc1 = __builtin_amdgcn_mfma_f32_32x32x16_bf16(pa, VB1, oacc1, 0,0,0);\
  } while(0)

__global__ __launch_bounds__(256, 2) void attn_fwd(const unsigned short* __restrict__ Qf,
                                                   const unsigned short* __restrict__ Kf,
                                                   const unsigned short* __restrict__ Vf,
                                                   unsigned short* __restrict__ O) {
  const int swzb = (blockIdx.x & 7) * 96 + (blockIdx.x >> 3);
  const int bh = swzb >> 5;          // 0..23
  const int qi = swzb & 31;          // 0..31
  const int tid = threadIdx.x;
  const int wave = tid >> 6, lane = tid & 63;
  const int g = wave >> 1, sub = wave & 1;
  const int l31 = lane & 31, hi = lane >> 5;
  const int tq = g ? (63 - qi) : qi;
  const int q0w = tq * 64 + sub * 32;      // wave's 32 q-rows start
  const int qb = tq * 2 + sub;

  // fragment-tile bases (bytes), all + lane*16
  const char* Qb_ = (const char*)Qf + (((size_t)bh * 128 + qb) * 4) * 1024 + lane * 16;
  const char* Kbh = (const char*)Kf + ((size_t)bh * 512) * 1024 + lane * 16;
  const char* Vbh = (const char*)Vf + ((size_t)bh * 512) * 1024 + lane * 16;

  bf16x8 qf[4];
  #pragma unroll
  for (int f = 0; f < 4; f++) qf[f] = *(const bf16x8*)(Qb_ + f * 1024);

  f32x16 oacc0 = {}, oacc1 = {};
  float m_i = -1e30f, l_i = 0.f;

  auto loadK = [&](KFrags& k, int c) {
    const char* p = Kbh + (size_t)c * 8192;
    #pragma unroll
    for (int g2 = 0; g2 < 2; g2++)
      #pragma unroll
      for (int f = 0; f < 4; f++)
        k.a[g2][f] = *(const bf16x8*)(p + g2 * 4096 + f * 1024);
  };

  auto body = [&](const KFrags& kc, KFrags* kn, int c, bool last) {
    // V loads for this chunk (used ~400cy later, after QK+softmax)
    bf16x8 vv[4][2];
    const char* vp = Vbh + (size_t)c * 8192;
    #pragma unroll
    for (int ks = 0; ks < 4; ks++) {
      vv[ks][0] = *(const bf16x8*)(vp + ks * 2048);
      vv[ks][1] = *(const bf16x8*)(vp + ks * 2048 + 1024);
    }
    if (kn) loadK(*kn, c + 1);          // K prefetch: one full body ahead

    const bool g1act = !last || (sub == 1);
    f32x16 s0 = {}, s1 = {};

    __builtin_amdgcn_s_setprio(1);
    #pragma unroll
    for (int f = 0; f < 4; f++)
      s0 = __builtin_amdgcn_mfma_f32_32x32x16_bf16(kc.a[0][f], qf[f], s0, 0, 0, 0);
    if (g1act) {
      #pragma unroll
      for (int f = 0; f < 4; f++)
        s1 = __builtin_amdgcn_mfma_f32_32x32x16_bf16(kc.a[1][f], qf[f], s1, 0, 0, 0);
    }
    __builtin_amdgcn_s_setprio(0);

    if (last) {   // diagonal 32-block: sub==0 masks s0, sub==1 masks s1
      if (sub == 0) {
        #pragma unroll
        for (int r = 0; r < 16; r++) {
          int kvo = (r & 3) + 8 * (r >> 2) + 4 * hi;
          if (kvo > l31) s0[r] = -1e30f;
        }
      } else {
        #pragma unroll
        for (int r = 0; r < 16; r++) {
          int kvo = (r & 3) + 8 * (r >> 2) + 4 * hi;
          if (kvo > l31) s1[r] = -1e30f;
        }
      }
    }

    // online softmax (lane owns q=l31; partner lane^32 has other kv-half)
    float pm = vmax16(s0);
    if (g1act) pm = fmaxf(pm, vmax16(s1));
    pm = fmaxf(pm, __shfl_xor(pm, 32));
    if (__any(pm > m_i + 10.f)) {        // defer-max THR=10 (log2 units)
      float nm = fmaxf(m_i, pm);
      float sc = fexp2(m_i - nm);
      m_i = nm; l_i *= sc;
      #pragma unroll
      for (int r = 0; r < 16; r++) {
        float scr = __shfl(sc, (r & 3) + 8 * (r >> 2) + 4 * hi);
        oacc0[r] *= scr; oacc1[r] *= scr;
      }
    }
    #pragma unroll
    for (int r = 0; r < 16; r++) s0[r] = fexp2(s0[r] - m_i);
    float ts = vsum16(s0);
    if (g1act) {
      #pragma unroll
      for (int r = 0; r < 16; r++) s1[r] = fexp2(s1[r] - m_i);
      ts += vsum16(s1);
    }
    ts += __shfl_xor(ts, 32);
    l_i += ts;

    __builtin_amdgcn_s_setprio(1);
    PVSTEP(s0, 0, vv[0][0], vv[0][1]);
    PVSTEP(s0, 8, vv[1][0], vv[1][1]);
    if (g1act) {
      PVSTEP(s1, 0, vv[2][0], vv[2][1]);
      PVSTEP(s1, 8, vv[3][0], vv[3][1]);
    }
    __builtin_amdgcn_s_setprio(0);
  };

  KFrags kA, kB;
  loadK(kA, 0);
  int c = 0;
  bool lastA = true;
  while (c < tq) {
    body(kA, &kB, c, false); c++;
    if (c == tq) { lastA = false; break; }
    body(kB, &kA, c, false); c++;
  }
  if (lastA) body(kA, nullptr, tq, true);
  else       body(kB, nullptr, tq, true);

  const int b = bh / NH, h = bh % NH;
  #pragma unroll
  for (int r = 0; r < 16; r++) {
    int qo = (r & 3) + 8 * (r >> 2) + 4 * hi;
    float lq = __shfl(l_i, qo);
    float inv = 1.0f / lq;
    size_t base = ((size_t)b * SL + q0w + qo) * D_MODEL + h * DHd;
    O[base + l31]      = bfc(oacc0[r] * inv);
    O[base + 32 + l31] = bfc(oacc1[r] * inv);
  }
}

// ---------------- launch ----------------
extern "C" void kernel_launch(void* const* d_in, const int* in_sizes, int n_in,
                              void* d_out, int out_size, void* d_ws, size_t ws_size,
                              hipStream_t stream) {
  (void)in_sizes; (void)n_in; (void)out_size; (void)ws_size;
  const float* x     = (const float*)d_in[0];
  const float* w_qkv = (const float*)d_in[1];
  const float* b_qkv = (const float*)d_in[2];
  const float* w_out = (const float*)d_in[3];
  const float* b_out = (const float*)d_in[4];
  float* out = (float*)d_out;

  unsigned short* p = (unsigned short*)d_ws;
  unsigned short* xb    = p; p += (size_t)BLr * D_MODEL;
  unsigned short* wqkvT = p; p += (size_t)N3 * D_MODEL;
  unsigned short* woutT = p; p += (size_t)D_MODEL * D_MODEL;
  unsigned short* Qf    = p; p += (size_t)NB * NH * SL * DHd;  // fragment-tiled, *log2e/8
  unsigned short* Kf    = p; p += (size_t)NB * NH * SL * DHd;  // fragment-tiled
  unsigned short* Vf    = p; p += (size_t)NB * NH * SL * DHd;  // fragment-tiled (V^T frags)
  unsigned short* Ob    = p;                                   // [b*l][768] bf16

  cast_f32_bf16<<<(BLr * D_MODEL / 4 + 255) / 256, 256, 0, stream>>>(x, xb, BLr * D_MODEL / 4);
  transpose_cast<<<dim3(N3 / 32, D_MODEL / 32), 256, 0, stream>>>(w_qkv, wqkvT, D_MODEL, N3);
  transpose_cast<<<dim3(D_MODEL / 32, D_MODEL / 32), 256, 0, stream>>>(w_out, woutT, D_MODEL, D_MODEL);
  gemm_bf16<0><<<dim3(BLr / 128, N3 / 128), 256, 0, stream>>>(xb, wqkvT, b_qkv, Qf, Kf, Vf,
                                                              BLr, N3, D_MODEL);
  attn_fwd<<<768, 256, 0, stream>>>(Qf, Kf, Vf, Ob);
  gemm_bf16<1><<<dim3(BLr / 128, D_MODEL / 128), 256, 0, stream>>>(Ob, woutT, b_out, out,
                                                                   nullptr, nullptr,
                                                                   BLr, D_MODEL, D_MODEL);
}